// Round 1
// baseline (41.850 us; speedup 1.0000x reference)
//
#include <hip/hip_runtime.h>
#include <math.h>

constexpr int IMG = 224;
constexpr int Bb  = 16;
constexpr int Vv  = 8;
constexpr int Nn  = 8192;
constexpr int Mm  = 1024;

__global__ __launch_bounds__(256) void calib_kernel(
    const float* __restrict__ pc,         // (B, N, 3)
    const float* __restrict__ mask,       // (B, V, IMG, IMG)
    const float* __restrict__ bounds,     // (B, V, M, 2)
    const float* __restrict__ inv_param,  // (B, V, 4, 4)
    const float* __restrict__ proj_fine,  // (B, V, N, 2)
    const float* __restrict__ proj_finez, // (B, V, N)
    const int*   __restrict__ view_p,     // scalar
    float*       __restrict__ out)        // (B, N, 3)
{
    const int view = *view_p;
    const int b = blockIdx.y;
    const int i = blockIdx.x * blockDim.x + threadIdx.x;

    // Stage normalized bounds + norms in LDS: (bx/224, by/224, |bd|^2, 0)
    __shared__ float4 s_bd[Mm];

    const float* bnd = bounds + (size_t)(b * Vv + view) * Mm * 2;
    for (int j = threadIdx.x; j < Mm; j += 256) {
        float bx  = bnd[2 * j];
        float by  = bnd[2 * j + 1];
        float bdx = bx / (float)IMG;           // exact IEEE div, matches ref
        float bdy = by / (float)IMG;
        float nrm = __fadd_rn(__fmul_rn(bdx, bdx), __fmul_rn(bdy, bdy));
        s_bd[j] = make_float4(bdx, bdy, nrm, 0.0f);
    }
    __syncthreads();

    if (i >= Nn) return;

    const size_t pf = (size_t)(b * Vv + view) * Nn + i;
    float px = proj_fine[2 * pf];
    float py = proj_fine[2 * pf + 1];

    // pxy = [x, IMG - y]; round half-to-even like jnp.round
    int i0 = (int)rintf(px);
    int i1 = (int)rintf((float)IMG - py);

    // padded-mask probe: mv[xi, yi], xi = clip(i1+1, 0, 225), yi = clip(i0+1, 0, 225)
    int xi = min(max(i1 + 1, 0), IMG + 1);
    int yi = min(max(i0 + 1, 0), IMG + 1);
    float mval = 0.0f;
    if (xi >= 1 && xi <= IMG && yi >= 1 && yi <= IMG)
        mval = mask[((size_t)(b * Vv + view) * IMG + (xi - 1)) * IMG + (yi - 1)];
    const bool use_back = (mval == 0.0f);

    // normalized query point
    float ox = (float)i0 / (float)IMG;
    float oy = (float)i1 / (float)IMG;
    float o2 = __fadd_rn(__fmul_rn(ox, ox), __fmul_rn(oy, oy));

    // argmin_j (o2 + |bd_j|^2 - 2*o.bd_j), first-index tie-break, exact np association
    float best  = INFINITY;
    int   bestj = 0;
    #pragma unroll 8
    for (int j = 0; j < Mm; ++j) {
        float4 bd  = s_bd[j];
        float  dot = __fadd_rn(__fmul_rn(ox, bd.x), __fmul_rn(oy, bd.y));
        float  d2  = __fadd_rn(__fadd_rn(o2, bd.z), __fmul_rn(-2.0f, dot));
        if (d2 < best) { best = d2; bestj = j; }
    }

    // back-projection: [nbx*z, nby*z, z, 1] @ inv_param[b, view][:, 0:3]
    float nbx = bnd[2 * bestj];
    float nby = bnd[2 * bestj + 1];
    float z   = proj_finez[pf];
    const float* ip = inv_param + (size_t)(b * Vv + view) * 16;
    float h0 = nbx * z, h1 = nby * z;
    float r0 = h0 * ip[0] + h1 * ip[4] + z * ip[8]  + ip[12];
    float r1 = h0 * ip[1] + h1 * ip[5] + z * ip[9]  + ip[13];
    float r2 = h0 * ip[2] + h1 * ip[6] + z * ip[10] + ip[14];

    const size_t ob = ((size_t)b * Nn + i) * 3;
    float c0 = pc[ob], c1 = pc[ob + 1], c2 = pc[ob + 2];
    out[ob]     = use_back ? r0 : c0;
    out[ob + 1] = use_back ? r1 : c1;
    out[ob + 2] = use_back ? r2 : c2;
}

extern "C" void kernel_launch(void* const* d_in, const int* in_sizes, int n_in,
                              void* d_out, int out_size, void* d_ws, size_t ws_size,
                              hipStream_t stream) {
    const float* pc         = (const float*)d_in[0];
    const float* mask       = (const float*)d_in[1];
    const float* bounds     = (const float*)d_in[2];
    const float* inv_param  = (const float*)d_in[3];
    const float* proj_fine  = (const float*)d_in[4];
    const float* proj_finez = (const float*)d_in[5];
    const int*   view_p     = (const int*)d_in[6];
    float* out = (float*)d_out;

    dim3 grid(Nn / 256, Bb);
    calib_kernel<<<grid, 256, 0, stream>>>(pc, mask, bounds, inv_param,
                                           proj_fine, proj_finez, view_p, out);
}

// Round 2
// 38.964 us; speedup vs baseline: 1.0741x; 1.0741x over previous
//
#include <hip/hip_runtime.h>
#include <math.h>

constexpr int IMG = 224;
constexpr int Bb  = 16;
constexpr int Vv  = 8;
constexpr int Nn  = 8192;
constexpr int Mm  = 1024;

// 4 lanes per point, 64 points per 256-thread block.
__global__ __launch_bounds__(256) void calib_kernel(
    const float* __restrict__ pc,         // (B, N, 3)
    const float* __restrict__ mask,       // (B, V, IMG, IMG)
    const float* __restrict__ bounds,     // (B, V, M, 2)
    const float* __restrict__ inv_param,  // (B, V, 4, 4)
    const float* __restrict__ proj_fine,  // (B, V, N, 2)
    const float* __restrict__ proj_finez, // (B, V, N)
    const int*   __restrict__ view_p,     // scalar
    float*       __restrict__ out)        // (B, N, 3)
{
    const int view = *view_p;
    const int b = blockIdx.y;
    const int s = threadIdx.x & 3;            // candidate slice (j mod 4)
    const int p_local = threadIdx.x >> 2;     // point within block
    const int i = blockIdx.x * 64 + p_local;  // global point index

    // LDS: (bx/224, by/224, |bd|^2, pad) per candidate
    __shared__ float4 s_bd[Mm];

    const float* bnd = bounds + (size_t)(b * Vv + view) * Mm * 2;
    for (int j = threadIdx.x; j < Mm; j += 256) {
        float2 bxy = reinterpret_cast<const float2*>(bnd)[j];
        float bdx = bxy.x / (float)IMG;   // exact IEEE div, matches ref
        float bdy = bxy.y / (float)IMG;
        float nrm = __fadd_rn(__fmul_rn(bdx, bdx), __fmul_rn(bdy, bdy));
        s_bd[j] = make_float4(bdx, bdy, nrm, 0.0f);
    }
    __syncthreads();

    const size_t pf = (size_t)(b * Vv + view) * Nn + i;
    float2 pxy = reinterpret_cast<const float2*>(proj_fine)[pf];

    // pxy = [x, IMG - y]; round half-to-even like jnp.round
    int i0 = (int)rintf(pxy.x);
    int i1 = (int)rintf((float)IMG - pxy.y);

    float ox = (float)i0 / (float)IMG;
    float oy = (float)i1 / (float)IMG;
    float o2 = __fadd_rn(__fmul_rn(ox, ox), __fmul_rn(oy, oy));
    // -2*o is exact (power-of-2 scale); fmul(n2ox,bx)+fmul(n2oy,by) is
    // bitwise-equal to -2*(ox*bx + oy*by), so d2 ordering/ties unchanged.
    float n2ox = __fmul_rn(-2.0f, ox);
    float n2oy = __fmul_rn(-2.0f, oy);

    // Two independent trackers (j mod 8 classes) to break the serial chain.
    float best0 = INFINITY, best1 = INFINITY;
    int   bj0 = 0, bj1 = 0;
    const float4* sp = s_bd + s;
    #pragma unroll 4
    for (int q = 0; q < Mm / 8; ++q) {
        float4 bd0 = sp[8 * q];        // j = 8q + s
        float4 bd1 = sp[8 * q + 4];    // j = 8q + 4 + s
        int j0 = 8 * q + s;
        float dn0 = __fadd_rn(__fmul_rn(n2ox, bd0.x), __fmul_rn(n2oy, bd0.y));
        float d20 = __fadd_rn(__fadd_rn(o2, bd0.z), dn0);
        if (d20 < best0) { best0 = d20; bj0 = j0; }
        float dn1 = __fadd_rn(__fmul_rn(n2ox, bd1.x), __fmul_rn(n2oy, bd1.y));
        float d21 = __fadd_rn(__fadd_rn(o2, bd1.z), dn1);
        if (d21 < best1) { best1 = d21; bj1 = j0 + 4; }
    }
    // Merge trackers lexicographically (equal d2 -> smaller j), matching
    // numpy first-index argmin exactly.
    if (best1 < best0 || (best1 == best0 && bj1 < bj0)) { best0 = best1; bj0 = bj1; }

    // Reduce across the 4 slice lanes.
    #pragma unroll
    for (int off = 1; off < 4; off <<= 1) {
        float bo = __shfl_xor(best0, off);
        int   jo = __shfl_xor(bj0, off);
        if (bo < best0 || (bo == best0 && jo < bj0)) { best0 = bo; bj0 = jo; }
    }

    if (s == 0) {
        // padded-mask probe
        int xi = min(max(i1 + 1, 0), IMG + 1);
        int yi = min(max(i0 + 1, 0), IMG + 1);
        float mval = 0.0f;
        if (xi >= 1 && xi <= IMG && yi >= 1 && yi <= IMG)
            mval = mask[((size_t)(b * Vv + view) * IMG + (xi - 1)) * IMG + (yi - 1)];
        const bool use_back = (mval == 0.0f);

        // back-projection: [nbx*z, nby*z, z, 1] @ inv_param[b, view][:, 0:3]
        float nbx = bnd[2 * bj0];
        float nby = bnd[2 * bj0 + 1];
        float z   = proj_finez[pf];
        const float* ip = inv_param + (size_t)(b * Vv + view) * 16;
        float h0 = nbx * z, h1 = nby * z;
        float r0 = h0 * ip[0] + h1 * ip[4] + z * ip[8]  + ip[12];
        float r1 = h0 * ip[1] + h1 * ip[5] + z * ip[9]  + ip[13];
        float r2 = h0 * ip[2] + h1 * ip[6] + z * ip[10] + ip[14];

        const size_t ob = ((size_t)b * Nn + i) * 3;
        float c0 = pc[ob], c1 = pc[ob + 1], c2 = pc[ob + 2];
        out[ob]     = use_back ? r0 : c0;
        out[ob + 1] = use_back ? r1 : c1;
        out[ob + 2] = use_back ? r2 : c2;
    }
}

extern "C" void kernel_launch(void* const* d_in, const int* in_sizes, int n_in,
                              void* d_out, int out_size, void* d_ws, size_t ws_size,
                              hipStream_t stream) {
    const float* pc         = (const float*)d_in[0];
    const float* mask       = (const float*)d_in[1];
    const float* bounds     = (const float*)d_in[2];
    const float* inv_param  = (const float*)d_in[3];
    const float* proj_fine  = (const float*)d_in[4];
    const float* proj_finez = (const float*)d_in[5];
    const int*   view_p     = (const int*)d_in[6];
    float* out = (float*)d_out;

    dim3 grid(Nn / 64, Bb);
    calib_kernel<<<grid, 256, 0, stream>>>(pc, mask, bounds, inv_param,
                                           proj_fine, proj_finez, view_p, out);
}

// Round 3
// 37.854 us; speedup vs baseline: 1.1056x; 1.0293x over previous
//
#include <hip/hip_runtime.h>
#include <math.h>

constexpr int IMG = 224;
constexpr int Bb  = 16;
constexpr int Vv  = 8;
constexpr int Nn  = 8192;
constexpr int Mm  = 1024;

typedef float sf8 __attribute__((ext_vector_type(8)));

// ---------- Kernel A: normalize bounds -> planar ws arrays ----------------
// ws layout: wsx[16][1024] | wsy[16][1024] | wsn[16][1024]  (192 KiB)
__global__ __launch_bounds__(256) void prep_kernel(
    const float* __restrict__ bounds, const int* __restrict__ view_p,
    float* __restrict__ ws)
{
    const int view = *view_p;
    const int b = blockIdx.x;
    const float* bnd = bounds + (size_t)(b * Vv + view) * Mm * 2;
    float* wsx = ws;
    float* wsy = ws + Bb * Mm;
    float* wsn = ws + 2 * Bb * Mm;
    for (int j = threadIdx.x; j < Mm; j += 256) {
        float2 bxy = reinterpret_cast<const float2*>(bnd)[j];
        float bdx = bxy.x / (float)IMG;   // exact IEEE div, matches ref
        float bdy = bxy.y / (float)IMG;
        float nrm = __fadd_rn(__fmul_rn(bdx, bdx), __fmul_rn(bdy, bdy));
        wsx[b * Mm + j] = bdx;
        wsy[b * Mm + j] = bdy;
        wsn[b * Mm + j] = nrm;
    }
}

// ---------- Kernel B: scalar-operand NN scan ------------------------------
// Block = 256 threads = 4 waves. Each block owns 64 points (lane = point);
// wave w scans candidate slice [256w, 256w+256) with candidates in SGPRs.
__global__ __launch_bounds__(256) void calib_kernel(
    const float* __restrict__ pc,         // (B, N, 3)
    const float* __restrict__ mask,       // (B, V, IMG, IMG)
    const float* __restrict__ bounds,     // (B, V, M, 2)
    const float* __restrict__ inv_param,  // (B, V, 4, 4)
    const float* __restrict__ proj_fine,  // (B, V, N, 2)
    const float* __restrict__ proj_finez, // (B, V, N)
    const int*   __restrict__ view_p,     // scalar
    const float* __restrict__ ws,         // normalized candidates (planar)
    float*       __restrict__ out)        // (B, N, 3)
{
    const int view = *view_p;
    const int b = blockIdx.y;
    const int l = threadIdx.x & 63;
    // wave id as a PROVABLY uniform value so candidate pointers live in SGPRs
    const int wu = __builtin_amdgcn_readfirstlane(threadIdx.x >> 6);
    const int i = blockIdx.x * 64 + l;

    const size_t pf = (size_t)(b * Vv + view) * Nn + i;
    float2 pxy = reinterpret_cast<const float2*>(proj_fine)[pf];

    int i0 = (int)rintf(pxy.x);                 // round half-to-even
    int i1 = (int)rintf((float)IMG - pxy.y);

    float ox = (float)i0 / (float)IMG;
    float oy = (float)i1 / (float)IMG;
    float o2 = __fadd_rn(__fmul_rn(ox, ox), __fmul_rn(oy, oy));
    // exact power-of-2 scale; ordering/ties of d2 unchanged vs ref form
    float n2ox = __fmul_rn(-2.0f, ox);
    float n2oy = __fmul_rn(-2.0f, oy);

    const float* wx = ws + (size_t)b * Mm + wu * 256;
    const float* wy = wx + Bb * Mm;
    const float* wn = wx + 2 * Bb * Mm;
    const int jbase = wu * 256;

    float best = INFINITY;
    int   bj   = 0;
    for (int q = 0; q < 32; ++q) {
        sf8 X, Y, Z;
        asm volatile("s_load_dwordx8 %0, %1, 0x0" : "=s"(X) : "s"(wx + 8 * q));
        asm volatile("s_load_dwordx8 %0, %1, 0x0" : "=s"(Y) : "s"(wy + 8 * q));
        asm volatile("s_load_dwordx8 %0, %1, 0x0" : "=s"(Z) : "s"(wn + 8 * q));
        // consumers depend on the waitcnt's outputs -> cannot be hoisted
        asm volatile("s_waitcnt lgkmcnt(0)" : "+s"(X), "+s"(Y), "+s"(Z));
        #pragma unroll
        for (int k = 0; k < 8; ++k) {
            float dn = __fadd_rn(__fmul_rn(n2ox, X[k]), __fmul_rn(n2oy, Y[k]));
            float d2 = __fadd_rn(__fadd_rn(o2, Z[k]), dn);
            int j = jbase + 8 * q + k;
            if (d2 < best) { best = d2; bj = j; }   // strict < = first-index
        }
    }

    // ---- merge the 4 wave slices (lexicographic: d2, then smaller j) ----
    __shared__ float s_best[4][64];
    __shared__ int   s_bj[4][64];
    s_best[wu][l] = best;
    s_bj[wu][l]   = bj;
    __syncthreads();

    if (threadIdx.x < 64) {
        float bestm = s_best[0][l];
        int   bjm   = s_bj[0][l];
        #pragma unroll
        for (int w = 1; w < 4; ++w) {
            float bw = s_best[w][l];
            int   jw = s_bj[w][l];
            if (bw < bestm || (bw == bestm && jw < bjm)) { bestm = bw; bjm = jw; }
        }

        // padded-mask probe
        int xi = min(max(i1 + 1, 0), IMG + 1);
        int yi = min(max(i0 + 1, 0), IMG + 1);
        float mval = 0.0f;
        if (xi >= 1 && xi <= IMG && yi >= 1 && yi <= IMG)
            mval = mask[((size_t)(b * Vv + view) * IMG + (xi - 1)) * IMG + (yi - 1)];
        const bool use_back = (mval == 0.0f);

        // back-projection: [nbx*z, nby*z, z, 1] @ inv_param[b, view][:, 0:3]
        const float* bnd = bounds + (size_t)(b * Vv + view) * Mm * 2;
        float nbx = bnd[2 * bjm];
        float nby = bnd[2 * bjm + 1];
        float z   = proj_finez[pf];
        const float* ip = inv_param + (size_t)(b * Vv + view) * 16;
        float h0 = nbx * z, h1 = nby * z;
        float r0 = h0 * ip[0] + h1 * ip[4] + z * ip[8]  + ip[12];
        float r1 = h0 * ip[1] + h1 * ip[5] + z * ip[9]  + ip[13];
        float r2 = h0 * ip[2] + h1 * ip[6] + z * ip[10] + ip[14];

        const size_t ob = ((size_t)b * Nn + i) * 3;
        float c0 = pc[ob], c1 = pc[ob + 1], c2 = pc[ob + 2];
        out[ob]     = use_back ? r0 : c0;
        out[ob + 1] = use_back ? r1 : c1;
        out[ob + 2] = use_back ? r2 : c2;
    }
}

// ---------- Fallback (R2 kernel) if ws is too small -----------------------
__global__ __launch_bounds__(256) void calib_fallback(
    const float* __restrict__ pc, const float* __restrict__ mask,
    const float* __restrict__ bounds, const float* __restrict__ inv_param,
    const float* __restrict__ proj_fine, const float* __restrict__ proj_finez,
    const int* __restrict__ view_p, float* __restrict__ out)
{
    const int view = *view_p;
    const int b = blockIdx.y;
    const int s = threadIdx.x & 3;
    const int p_local = threadIdx.x >> 2;
    const int i = blockIdx.x * 64 + p_local;

    __shared__ float4 s_bd[Mm];
    const float* bnd = bounds + (size_t)(b * Vv + view) * Mm * 2;
    for (int j = threadIdx.x; j < Mm; j += 256) {
        float2 bxy = reinterpret_cast<const float2*>(bnd)[j];
        float bdx = bxy.x / (float)IMG;
        float bdy = bxy.y / (float)IMG;
        float nrm = __fadd_rn(__fmul_rn(bdx, bdx), __fmul_rn(bdy, bdy));
        s_bd[j] = make_float4(bdx, bdy, nrm, 0.0f);
    }
    __syncthreads();

    const size_t pf = (size_t)(b * Vv + view) * Nn + i;
    float2 pxy = reinterpret_cast<const float2*>(proj_fine)[pf];
    int i0 = (int)rintf(pxy.x);
    int i1 = (int)rintf((float)IMG - pxy.y);
    float ox = (float)i0 / (float)IMG;
    float oy = (float)i1 / (float)IMG;
    float o2 = __fadd_rn(__fmul_rn(ox, ox), __fmul_rn(oy, oy));
    float n2ox = __fmul_rn(-2.0f, ox);
    float n2oy = __fmul_rn(-2.0f, oy);

    float best0 = INFINITY, best1 = INFINITY;
    int bj0 = 0, bj1 = 0;
    const float4* sp = s_bd + s;
    #pragma unroll 4
    for (int q = 0; q < Mm / 8; ++q) {
        float4 bd0 = sp[8 * q];
        float4 bd1 = sp[8 * q + 4];
        int j0 = 8 * q + s;
        float dn0 = __fadd_rn(__fmul_rn(n2ox, bd0.x), __fmul_rn(n2oy, bd0.y));
        float d20 = __fadd_rn(__fadd_rn(o2, bd0.z), dn0);
        if (d20 < best0) { best0 = d20; bj0 = j0; }
        float dn1 = __fadd_rn(__fmul_rn(n2ox, bd1.x), __fmul_rn(n2oy, bd1.y));
        float d21 = __fadd_rn(__fadd_rn(o2, bd1.z), dn1);
        if (d21 < best1) { best1 = d21; bj1 = j0 + 4; }
    }
    if (best1 < best0 || (best1 == best0 && bj1 < bj0)) { best0 = best1; bj0 = bj1; }
    #pragma unroll
    for (int off = 1; off < 4; off <<= 1) {
        float bo = __shfl_xor(best0, off);
        int   jo = __shfl_xor(bj0, off);
        if (bo < best0 || (bo == best0 && jo < bj0)) { best0 = bo; bj0 = jo; }
    }
    if (s == 0) {
        int xi = min(max(i1 + 1, 0), IMG + 1);
        int yi = min(max(i0 + 1, 0), IMG + 1);
        float mval = 0.0f;
        if (xi >= 1 && xi <= IMG && yi >= 1 && yi <= IMG)
            mval = mask[((size_t)(b * Vv + view) * IMG + (xi - 1)) * IMG + (yi - 1)];
        const bool use_back = (mval == 0.0f);
        float nbx = bnd[2 * bj0];
        float nby = bnd[2 * bj0 + 1];
        float z   = proj_finez[pf];
        const float* ip = inv_param + (size_t)(b * Vv + view) * 16;
        float h0 = nbx * z, h1 = nby * z;
        float r0 = h0 * ip[0] + h1 * ip[4] + z * ip[8]  + ip[12];
        float r1 = h0 * ip[1] + h1 * ip[5] + z * ip[9]  + ip[13];
        float r2 = h0 * ip[2] + h1 * ip[6] + z * ip[10] + ip[14];
        const size_t ob = ((size_t)b * Nn + i) * 3;
        float c0 = pc[ob], c1 = pc[ob + 1], c2 = pc[ob + 2];
        out[ob]     = use_back ? r0 : c0;
        out[ob + 1] = use_back ? r1 : c1;
        out[ob + 2] = use_back ? r2 : c2;
    }
}

extern "C" void kernel_launch(void* const* d_in, const int* in_sizes, int n_in,
                              void* d_out, int out_size, void* d_ws, size_t ws_size,
                              hipStream_t stream) {
    const float* pc         = (const float*)d_in[0];
    const float* mask       = (const float*)d_in[1];
    const float* bounds     = (const float*)d_in[2];
    const float* inv_param  = (const float*)d_in[3];
    const float* proj_fine  = (const float*)d_in[4];
    const float* proj_finez = (const float*)d_in[5];
    const int*   view_p     = (const int*)d_in[6];
    float* out = (float*)d_out;

    const size_t ws_need = (size_t)3 * Bb * Mm * sizeof(float);  // 192 KiB
    if (ws_size >= ws_need) {
        float* ws = (float*)d_ws;
        prep_kernel<<<dim3(Bb), 256, 0, stream>>>(bounds, view_p, ws);
        dim3 grid(Nn / 64, Bb);
        calib_kernel<<<grid, 256, 0, stream>>>(pc, mask, bounds, inv_param,
                                               proj_fine, proj_finez, view_p,
                                               ws, out);
    } else {
        dim3 grid(Nn / 64, Bb);
        calib_fallback<<<grid, 256, 0, stream>>>(pc, mask, bounds, inv_param,
                                                 proj_fine, proj_finez, view_p,
                                                 out);
    }
}